// Round 15
// baseline (206.808 us; speedup 1.0000x reference)
//
#include <hip/hip_runtime.h>
#include <math.h>

// ---------------------------------------------------------------------------
// GCN, atomic-free aggregation via per-call CSR (bucket by dst):
//   deg count (single-pass) -> block scan(+dinv) -> add_offsets (fused bsum
//   scan) -> fill (dst-partitioned, XCD-local, u16)               [once]
//   gemm1 (MFMA 16x16x32 bf16, W frags in VGPRs, zero LDS): G1=(x@W1)*dinv
//   aggmm<64>: y1=relu(dinv*(G1self+gather)+b1) -> LDS[16][72] -> MFMA
//              G2=(Y1@W2)*dinv   [agg + next-layer GEMM fused per 16 nodes]
//   aggmm<40>: same with W3 -> G3
//   agg40_lsm: y3=relu(...b3); out=log_softmax(y3)
// aggmm: 512 thr / 8 waves, 2 nodes per wave, 4-deep gather pipeline (rounds
// e and e+8 for both nodes issued before accumulation; 4 accumulator banks).
// Diagnostic ledger (why gather micro-opts are exhausted): r11 fusion -25MB
// HBM = -2us (not HBM-bound); r12 plane-split = regression (not L2-capacity-
// bound); r13 2x TLP = -1.3% (not wave-starved); r14 2x chain ILP = -1.2%.
// Gather runs ~2.9TB/s effective on random 128B lines from a 6.4MB set with
// no pipe saturated -> fabric/L2-miss request-rate floor.
// count_deg is UNPARTITIONED: the 8x partitioning only ever paid for fill's
// cidx write-amp (r3: 25x); deg is a 200KB int-add target, no amp — the 8x
// edge re-read (25.6MB) was pure overhead.
// Gather: lane=(grp<<3)|sub, uint4 (8 bf16), 8 edge rows/instr, butterfly
// shfl_xor(8|16|32). r7: big reg tiles crater occupancy. r9: LDS gemv is
// LDS-pipe-bound. MFMA layouts (guide m89/m97).
// cidx u16 (N_NODES=50000<65536).
// NOTE: no hipMemsetAsync — rocclr fillBuffer took 45.9us for 195KB in-graph.
// ---------------------------------------------------------------------------

#define DF 64
#define TB 256
#define NPART 8

typedef __attribute__((ext_vector_type(8))) short bf16x8;
typedef __attribute__((ext_vector_type(4))) float f32x4;

__device__ __forceinline__ unsigned short f2bf(float f) {
    union { float f; unsigned u; } c; c.f = f;
    unsigned u = c.u;
    return (unsigned short)((u + 0x7fffu + ((u >> 16) & 1u)) >> 16);   // RNE
}
__device__ __forceinline__ float bf2f(unsigned short h) {
    union { unsigned u; float f; } c; c.u = ((unsigned)h) << 16;
    return c.f;
}
__device__ __forceinline__ void acc_bf16x8(uint4 v, float* a) {
    a[0] += bf2f((unsigned short)(v.x & 0xffffu));
    a[1] += bf2f((unsigned short)(v.x >> 16));
    a[2] += bf2f((unsigned short)(v.y & 0xffffu));
    a[3] += bf2f((unsigned short)(v.y >> 16));
    a[4] += bf2f((unsigned short)(v.z & 0xffffu));
    a[5] += bf2f((unsigned short)(v.z >> 16));
    a[6] += bf2f((unsigned short)(v.w & 0xffffu));
    a[7] += bf2f((unsigned short)(v.w >> 16));
}
__device__ __forceinline__ void acc_bf16x4(uint2 v, float* a) {
    a[0] += bf2f((unsigned short)(v.x & 0xffffu));
    a[1] += bf2f((unsigned short)(v.x >> 16));
    a[2] += bf2f((unsigned short)(v.y & 0xffffu));
    a[3] += bf2f((unsigned short)(v.y >> 16));
}

__global__ void zero_int_kernel(int* __restrict__ p, int n) {
    int i = blockIdx.x * blockDim.x + threadIdx.x;
    if (i < n) p[i] = 0;
}

// single pass: deg is a 200KB int-add target, no write-amplification issue
__global__ void count_deg_kernel(const int* __restrict__ dst, int* __restrict__ deg, int e) {
    int i = blockIdx.x * blockDim.x + threadIdx.x;
    if (i < e) atomicAdd(&deg[dst[i]], 1);
}

// per-block exclusive scan of deg -> ex (partial), block totals -> bsum; also dinv
__global__ void scan_block_kernel(const int* __restrict__ deg, int* __restrict__ ex,
                                  int* __restrict__ bsum, float* __restrict__ dinv, int n) {
    __shared__ int s[TB];
    const int t = threadIdx.x;
    const int i = blockIdx.x * TB + t;
    int v = (i < n) ? deg[i] : 0;
    if (i < n) dinv[i] = rsqrtf((float)(v + 1));   // +1 self-loop
    s[t] = v; __syncthreads();
#pragma unroll
    for (int o = 1; o < TB; o <<= 1) {
        int u = (t >= o) ? s[t - o] : 0;
        __syncthreads();
        s[t] += u;
        __syncthreads();
    }
    if (i < n) ex[i] = s[t] - v;
    if (t == TB - 1) bsum[blockIdx.x] = s[TB - 1];
}

// each block redundantly scans bsum (nb <= 256) in LDS, then offsets its slice
__global__ void add_offsets_kernel(int* __restrict__ ex, const int* __restrict__ bsum,
                                   int* __restrict__ cursor, int n, int nb) {
    __shared__ int s[TB];
    const int t = threadIdx.x;
    int v = (t < nb) ? bsum[t] : 0;
    s[t] = v; __syncthreads();
#pragma unroll
    for (int o = 1; o < TB; o <<= 1) {
        int u = (t >= o) ? s[t - o] : 0;
        __syncthreads();
        s[t] += u;
        __syncthreads();
    }
    const int boff = (blockIdx.x > 0) ? s[blockIdx.x - 1] : 0;
    const int i = blockIdx.x * TB + t;
    if (i < n) {
        int r = ex[i] + boff;
        ex[i] = r;
        cursor[i] = r;
    }
}

__global__ void fill_csr_part_kernel(const int* __restrict__ src, const int* __restrict__ dst,
                                     int* __restrict__ cursor,
                                     unsigned short* __restrict__ cidx, int e, int psize) {
    const int p   = blockIdx.x & (NPART - 1);
    const int sl  = blockIdx.x / NPART;
    const int nsl = gridDim.x / NPART;
    const int lo = p * psize, hi = lo + psize;
    for (int i = sl * TB + threadIdx.x; i < e; i += nsl * TB) {
        int d = dst[i];
        if (d >= lo && d < hi) {
            int pos = atomicAdd(&cursor[d], 1);
            cidx[pos] = (unsigned short)src[i];
        }
    }
}

// G[M x 64](bf16) = (X[M x 64] @ W1[64 x 64]) * dinv[row], via MFMA. Layer 1.
__global__ __launch_bounds__(256) void gemm_mfma_kernel(
        const float* __restrict__ X, const float* __restrict__ W,
        const float* __restrict__ dinv, unsigned short* __restrict__ G, int M) {
    const int lane = threadIdx.x & 63;
    const int wid  = threadIdx.x >> 6;         // 0..3
    const int t    = blockIdx.x * 4 + wid;     // row-tile index
    const int nt   = (M + 15) >> 4;
    if (t >= nt) return;
    const int n = lane & 15;
    const int g = lane >> 4;

    bf16x8 bf[4][2];
#pragma unroll
    for (int ct = 0; ct < 4; ++ct) {
        const int c = ct * 16 + n;
#pragma unroll
        for (int ks = 0; ks < 2; ++ks)
#pragma unroll
            for (int j = 0; j < 8; ++j)
                bf[ct][ks][j] = (short)f2bf(W[(ks * 32 + g * 8 + j) * 64 + c]);
    }

    const int row_a = t * 16 + n;
    const int ra = (row_a < M) ? row_a : (M - 1);
    bf16x8 af[2];
#pragma unroll
    for (int ks = 0; ks < 2; ++ks) {
        float4 p0 = *(const float4*)(X + (size_t)ra * 64 + ks * 32 + g * 8);
        float4 p1 = *(const float4*)(X + (size_t)ra * 64 + ks * 32 + g * 8 + 4);
        af[ks][0] = (short)f2bf(p0.x); af[ks][1] = (short)f2bf(p0.y);
        af[ks][2] = (short)f2bf(p0.z); af[ks][3] = (short)f2bf(p0.w);
        af[ks][4] = (short)f2bf(p1.x); af[ks][5] = (short)f2bf(p1.y);
        af[ks][6] = (short)f2bf(p1.z); af[ks][7] = (short)f2bf(p1.w);
    }

    const int rbase = t * 16 + g * 4;
    float di[4];
#pragma unroll
    for (int r = 0; r < 4; ++r) {
        int rr = rbase + r;
        di[r] = dinv[(rr < M) ? rr : (M - 1)];
    }

#pragma unroll
    for (int ct = 0; ct < 4; ++ct) {
        f32x4 acc = {0.f, 0.f, 0.f, 0.f};
        acc = __builtin_amdgcn_mfma_f32_16x16x32_bf16(af[0], bf[ct][0], acc, 0, 0, 0);
        acc = __builtin_amdgcn_mfma_f32_16x16x32_bf16(af[1], bf[ct][1], acc, 0, 0, 0);
        const int col = ct * 16 + n;
#pragma unroll
        for (int r = 0; r < 4; ++r) {
            const int row = rbase + r;
            if (row < M)
                G[(size_t)row * 64 + col] = f2bf(acc[r] * di[r]);
        }
    }
}

// Fused: aggregate 16 nodes (2 per wave, 8 waves, 4-deep gather pipeline) +
// next-layer MFMA GEMM.
template <int NCO>
__global__ __launch_bounds__(512) void aggmm_kernel(
        const unsigned short* __restrict__ G,
        const int* __restrict__ rowptr, const int* __restrict__ deg,
        const unsigned short* __restrict__ cidx,
        const float* __restrict__ dinv, const float* __restrict__ b,
        const float* __restrict__ Wn,
        unsigned short* __restrict__ Gout, int M) {
    __shared__ unsigned short Ys[16][72];      // +8 pad: stride 144B
    __shared__ float ds[16];
    const int tid  = threadIdx.x;
    const int lane = tid & 63;
    const int wid  = tid >> 6;                 // 0..7
    const int base = blockIdx.x * 16;
    const int grp = lane >> 3;                 // 0..7 edge slot
    const int sub = lane & 7;                  // 0..7 col octet
    const int n16 = lane & 15;
    const int g16 = lane >> 4;

    // B fragments for MFMA waves (col tile = wid), loaded before agg
    const bool wactive = (wid * 16 < NCO);     // wid<4 (64) or wid<3 (40)
    bf16x8 bf[2];
    if (wactive) {
        const int c = wid * 16 + n16;
#pragma unroll
        for (int ks = 0; ks < 2; ++ks)
#pragma unroll
            for (int j = 0; j < 8; ++j) {
                const int k = ks * 32 + g16 * 8 + j;
                float w = (c < NCO) ? Wn[k * NCO + c] : 0.f;
                bf[ks][j] = (short)f2bf(w);
            }
    }

    // agg phase: wave wid owns rows wid*2, wid*2+1; 4-deep pipelined gather
    const int nrow0 = wid * 2;
    const int node0 = min(base + nrow0, M - 1);        // clamped: garbage ok
    const int node1 = min(base + nrow0 + 1, M - 1);
    const int start0 = rowptr[node0], cnt0 = deg[node0];
    const int start1 = rowptr[node1], cnt1 = deg[node1];

    float a0[8] = {0.f, 0.f, 0.f, 0.f, 0.f, 0.f, 0.f, 0.f};
    float a1[8] = {0.f, 0.f, 0.f, 0.f, 0.f, 0.f, 0.f, 0.f};
    float c0[8] = {0.f, 0.f, 0.f, 0.f, 0.f, 0.f, 0.f, 0.f};
    float c1[8] = {0.f, 0.f, 0.f, 0.f, 0.f, 0.f, 0.f, 0.f};

    if (cnt0 <= 64 && cnt1 <= 64) {
        // fast path: both cidx chunks up front; rounds e and e+8 for both
        // nodes issued together -> up to 4 loads in flight per wave
        int idx0 = (lane < cnt0) ? (int)cidx[start0 + lane] : 0;
        int idx1 = (lane < cnt1) ? (int)cidx[start1 + lane] : 0;
        const int cmax = max(cnt0, cnt1);
        for (int e = grp; e < cmax; e += 16) {
            const int e2 = e + 8;
            const bool pa0 = e < cnt0,  pa1 = e < cnt1;
            const bool pb0 = e2 < cnt0, pb1 = e2 < cnt1;
            int sa0 = __shfl(idx0, e, 64);
            int sa1 = __shfl(idx1, e, 64);
            int sb0 = __shfl(idx0, e2 & 63, 64);
            int sb1 = __shfl(idx1, e2 & 63, 64);
            uint4 va0, va1, vb0, vb1;
            if (pa0) va0 = *(const uint4*)(G + (size_t)sa0 * 64 + sub * 8);
            if (pa1) va1 = *(const uint4*)(G + (size_t)sa1 * 64 + sub * 8);
            if (pb0) vb0 = *(const uint4*)(G + (size_t)sb0 * 64 + sub * 8);
            if (pb1) vb1 = *(const uint4*)(G + (size_t)sb1 * 64 + sub * 8);
            if (pa0) acc_bf16x8(va0, a0);
            if (pa1) acc_bf16x8(va1, a1);
            if (pb0) acc_bf16x8(vb0, c0);
            if (pb1) acc_bf16x8(vb1, c1);
        }
    } else {
        // slow path (deg>64, rare): sequential chunked per node
        for (int which = 0; which < 2; ++which) {
            float* a = which ? a1 : a0;
            const int start = which ? start1 : start0;
            const int cnt   = which ? cnt1 : cnt0;
            for (int bs = 0; bs < cnt; bs += 64) {
                const int nthis = min(64, cnt - bs);
                int myidx = (lane < nthis) ? (int)cidx[start + bs + lane] : 0;
                for (int j = grp; j < nthis; j += 8) {
                    int s = __shfl(myidx, j, 64);
                    uint4 v = *(const uint4*)(G + (size_t)s * 64 + sub * 8);
                    acc_bf16x8(v, a);
                }
            }
        }
    }
#pragma unroll
    for (int k = 0; k < 8; ++k) { a0[k] += c0[k]; a1[k] += c1[k]; }
    // butterflies (both nodes interleaved for ILP)
#pragma unroll
    for (int k = 0; k < 8; ++k) {
        a0[k] += __shfl_xor(a0[k], 8, 64);
        a1[k] += __shfl_xor(a1[k], 8, 64);
        a0[k] += __shfl_xor(a0[k], 16, 64);
        a1[k] += __shfl_xor(a1[k], 16, 64);
        a0[k] += __shfl_xor(a0[k], 32, 64);
        a1[k] += __shfl_xor(a1[k], 32, 64);
    }
    if (grp == 0) {
#pragma unroll
        for (int i = 0; i < 2; ++i) {
            const float* a = i ? a1 : a0;
            const int node = i ? node1 : node0;
            uint4 sv = *(const uint4*)(G + (size_t)node * 64 + sub * 8);
            float4 b0 = *(const float4*)(b + sub * 8);
            float4 b1 = *(const float4*)(b + sub * 8 + 4);
            const float di = dinv[node];
            float v[8];
            v[0] = fmaxf((a[0] + bf2f((unsigned short)(sv.x & 0xffffu))) * di + b0.x, 0.f);
            v[1] = fmaxf((a[1] + bf2f((unsigned short)(sv.x >> 16)))     * di + b0.y, 0.f);
            v[2] = fmaxf((a[2] + bf2f((unsigned short)(sv.y & 0xffffu))) * di + b0.z, 0.f);
            v[3] = fmaxf((a[3] + bf2f((unsigned short)(sv.y >> 16)))     * di + b0.w, 0.f);
            v[4] = fmaxf((a[4] + bf2f((unsigned short)(sv.z & 0xffffu))) * di + b1.x, 0.f);
            v[5] = fmaxf((a[5] + bf2f((unsigned short)(sv.z >> 16)))     * di + b1.y, 0.f);
            v[6] = fmaxf((a[6] + bf2f((unsigned short)(sv.w & 0xffffu))) * di + b1.z, 0.f);
            v[7] = fmaxf((a[7] + bf2f((unsigned short)(sv.w >> 16)))     * di + b1.w, 0.f);
            uint4 o;
            o.x = (unsigned)f2bf(v[0]) | ((unsigned)f2bf(v[1]) << 16);
            o.y = (unsigned)f2bf(v[2]) | ((unsigned)f2bf(v[3]) << 16);
            o.z = (unsigned)f2bf(v[4]) | ((unsigned)f2bf(v[5]) << 16);
            o.w = (unsigned)f2bf(v[6]) | ((unsigned)f2bf(v[7]) << 16);
            *((uint4*)&Ys[nrow0 + i][sub * 8]) = o;
            if (sub == 0) ds[nrow0 + i] = di;
        }
    }
    __syncthreads();

    // MFMA phase: wave wid (<NCO/16) -> col tile [wid*16, wid*16+16)
    if (!wactive) return;
    bf16x8 af[2];
#pragma unroll
    for (int ks = 0; ks < 2; ++ks)
        af[ks] = *(const bf16x8*)&Ys[n16][ks * 32 + g16 * 8];
    f32x4 acc = {0.f, 0.f, 0.f, 0.f};
    acc = __builtin_amdgcn_mfma_f32_16x16x32_bf16(af[0], bf[0], acc, 0, 0, 0);
    acc = __builtin_amdgcn_mfma_f32_16x16x32_bf16(af[1], bf[1], acc, 0, 0, 0);
    const int col = wid * 16 + n16;
#pragma unroll
    for (int r = 0; r < 4; ++r) {
        const int row = base + g16 * 4 + r;
        if (row < M && col < NCO)
            Gout[(size_t)row * NCO + col] = f2bf(acc[r] * ds[g16 * 4 + r]);
    }
}

// NC=40 aggregation + fused log_softmax. lane = grp(2b)*16 + sub(4b);
// lane owns cols [sub*4, sub*4+4); 4 edge rows per instruction.
__global__ void agg40_lsm_kernel(const unsigned short* __restrict__ G,
                                 const int* __restrict__ rowptr, const int* __restrict__ deg,
                                 const unsigned short* __restrict__ cidx,
                                 const float* __restrict__ dinv, const float* __restrict__ b,
                                 float* __restrict__ Y, int M) {
    constexpr int NC = 40;
    constexpr int NQ = 10;
    const int lane = threadIdx.x & 63;
    const int node = blockIdx.x * 4 + (threadIdx.x >> 6);
    if (node >= M) return;
    const int grp = lane >> 4;                 // 0..3
    const int sub = lane & 15;                 // 0..15
    const bool act = (sub < NQ);
    const int start = rowptr[node];
    const int cnt = deg[node];

    float a[4] = {0.f, 0.f, 0.f, 0.f};
    float c[4] = {0.f, 0.f, 0.f, 0.f};

    for (int base = 0; base < cnt; base += 64) {
        const int nthis = min(64, cnt - base);
        int myidx = (lane < nthis) ? (int)cidx[start + base + lane] : 0;
        int j = 0;
        for (; j + 8 <= nthis; j += 8) {
            int s0 = __shfl(myidx, j + grp, 64);
            int s1 = __shfl(myidx, j + 4 + grp, 64);
            if (act) {
                uint2 v0 = *(const uint2*)(G + (size_t)s0 * NC + sub * 4);
                uint2 v1 = *(const uint2*)(G + (size_t)s1 * NC + sub * 4);
                acc_bf16x4(v0, a);
                acc_bf16x4(v1, c);
            }
        }
        if (j + 4 <= nthis) {
            int s0 = __shfl(myidx, j + grp, 64);
            if (act) {
                uint2 v0 = *(const uint2*)(G + (size_t)s0 * NC + sub * 4);
                acc_bf16x4(v0, a);
            }
            j += 4;
        }
        const int rem = nthis - j;             // 0..3
        if (grp < rem) {
            int s0 = __shfl(myidx, j + grp, 64);
            if (act) {
                uint2 v0 = *(const uint2*)(G + (size_t)s0 * NC + sub * 4);
                acc_bf16x4(v0, c);
            }
        }
    }
#pragma unroll
    for (int k = 0; k < 4; ++k) a[k] += c[k];
#pragma unroll
    for (int k = 0; k < 4; ++k) {
        a[k] += __shfl_xor(a[k], 16, 64);
        a[k] += __shfl_xor(a[k], 32, 64);
    }
    float v[4];
    {
        float self[4] = {0.f, 0.f, 0.f, 0.f};
        float4 bb = make_float4(0.f, 0.f, 0.f, 0.f);
        if (act) {
            uint2 sv = *(const uint2*)(G + (size_t)node * NC + sub * 4);
            self[0] = bf2f((unsigned short)(sv.x & 0xffffu));
            self[1] = bf2f((unsigned short)(sv.x >> 16));
            self[2] = bf2f((unsigned short)(sv.y & 0xffffu));
            self[3] = bf2f((unsigned short)(sv.y >> 16));
            bb = *(const float4*)(b + sub * 4);
        }
        const float di = dinv[node];
        v[0] = fmaxf((a[0] + self[0]) * di + bb.x, 0.f);
        v[1] = fmaxf((a[1] + self[1]) * di + bb.y, 0.f);
        v[2] = fmaxf((a[2] + self[2]) * di + bb.z, 0.f);
        v[3] = fmaxf((a[3] + self[3]) * di + bb.w, 0.f);
    }
    float m = act ? fmaxf(fmaxf(v[0], v[1]), fmaxf(v[2], v[3])) : -INFINITY;
#pragma unroll
    for (int o = 1; o < 16; o <<= 1) m = fmaxf(m, __shfl_xor(m, o, 64));
    float es = act ? (expf(v[0] - m) + expf(v[1] - m) + expf(v[2] - m) + expf(v[3] - m)) : 0.f;
#pragma unroll
    for (int o = 1; o < 16; o <<= 1) es += __shfl_xor(es, o, 64);
    const float ls = logf(es);
    if (act && grp == 0) {
        *((float4*)(Y + (size_t)node * NC + sub * 4)) =
            make_float4(v[0] - m - ls, v[1] - m - ls, v[2] - m - ls, v[3] - m - ls);
    }
}

extern "C" void kernel_launch(void* const* d_in, const int* in_sizes, int n_in,
                              void* d_out, int out_size, void* d_ws, size_t ws_size,
                              hipStream_t stream) {
    const float* x  = (const float*)d_in[0];
    const int*   ei = (const int*)d_in[1];        // [2, E] int32
    const float* W1 = (const float*)d_in[2];
    const float* b1 = (const float*)d_in[3];
    const float* W2 = (const float*)d_in[4];
    const float* b2 = (const float*)d_in[5];
    const float* W3 = (const float*)d_in[6];
    const float* b3 = (const float*)d_in[7];
    float* out = (float*)d_out;

    const int M  = in_sizes[0] / DF;              // 50000
    const int E  = in_sizes[1] / 2;               // 800000
    (void)ws_size; (void)n_in; (void)out_size;

    const int* src = ei;
    const int* dst = ei + E;

    const size_t Ma = ((size_t)M + 63) & ~63ull;
    const size_t Ea = ((size_t)E + 63) & ~63ull;

    // workspace layout
    int* deg    = (int*)d_ws;                            // Ma
    int* rowptr = deg + Ma;                              // Ma
    int* cursor = rowptr + Ma;                           // Ma
    int* bsum   = cursor + Ma;                           // 256
    unsigned short* cidx = (unsigned short*)(bsum + 256);        // Ea (u16)
    float* dinv = (float*)(cidx + Ea);                   // Ma
    unsigned short* G0 = (unsigned short*)(dinv + Ma);           // Ma*64 (bf16)
    unsigned short* G1 = G0 + Ma * DF;                   // Ma*64 (bf16)

    const int gN = (M + TB - 1) / TB;
    const int gE = (E + TB - 1) / TB;
    const int nb = gN;                   // scan blocks (196 <= 256)
    const int psize = (M + NPART - 1) / NPART;
    const int partGrd = NPART * 96;      // 8 partitions x 96 slices

    // --- CSR build + dinv (once, reused by all 3 layers) ---
    zero_int_kernel<<<gN, TB, 0, stream>>>(deg, M);
    count_deg_kernel<<<gE, TB, 0, stream>>>(dst, deg, E);
    scan_block_kernel<<<nb, TB, 0, stream>>>(deg, rowptr, bsum, dinv, M);
    add_offsets_kernel<<<nb, TB, 0, stream>>>(rowptr, bsum, cursor, M, nb);
    fill_csr_part_kernel<<<partGrd, TB, 0, stream>>>(src, dst, cursor, cidx, E, psize);

    const int nt      = (M + 15) / 16;            // 16-row tiles
    const int gemmGrd = (nt + 3) / 4;             // 4 waves/block (layer-1 gemm)
    const int fusGrd  = nt;                       // 16 nodes/block (fused)
    const int aggGrd  = (M + 3) / 4;

    // layer-1 dense transform
    gemm_mfma_kernel<<<gemmGrd, TB, 0, stream>>>(x, W1, dinv, G0, M);
    // layer-1 aggregate + layer-2 GEMM (fused; 4-deep pipelined gather)
    aggmm_kernel<64><<<fusGrd, 512, 0, stream>>>(G0, rowptr, deg, cidx, dinv, b1, W2, G1, M);
    // layer-2 aggregate + layer-3 GEMM (fused)
    aggmm_kernel<40><<<fusGrd, 512, 0, stream>>>(G1, rowptr, deg, cidx, dinv, b2, W3, G0, M);
    // layer-3 aggregate + log_softmax
    agg40_lsm_kernel<<<aggGrd, TB, 0, stream>>>(G0, rowptr, deg, cidx, dinv, b3, out, M);
}

// Round 16
// 190.082 us; speedup vs baseline: 1.0880x; 1.0880x over previous
//
#include <hip/hip_runtime.h>
#include <math.h>

// ---------------------------------------------------------------------------
// GCN, atomic-free aggregation via per-call CSR (bucket by dst):
//   deg count (dst-partitioned) -> block scan(+dinv) -> add_offsets (fused
//   bsum scan) -> fill (dst-partitioned, XCD-local, u16)          [once]
//   gemm1 (MFMA 16x16x32 bf16, W frags in VGPRs, zero LDS): G1=(x@W1)*dinv
//   aggmm<64>: y1=relu(dinv*(G1self+gather)+b1) -> LDS[16][72] -> MFMA
//              G2=(Y1@W2)*dinv   [agg + next-layer GEMM fused per 16 nodes]
//   aggmm<40>: same with W3 -> G3
//   agg40_lsm: y3=relu(...b3); out=log_softmax(y3)
// aggmm: 512 thr / 8 waves, 2 nodes per wave, two gather chains interleaved.
// THIS IS THE r14 CHAMPION (189.7us), reverted after r15's regression.
// Complete diagnostic ledger on the gather (all ~null or worse):
//   r11 fusion -25MB HBM        = -2us    (not HBM-bound)
//   r12 plane split (6.4->3.2MB)= +34us   (not L2-capacity-bound)
//   r13 2x TLP (8 waves/block)  = -1.3%   (not wave-starved)
//   r14 2x chain ILP            = -1.2%   (marginal chain slack)
//   r15 4x pipeline + un-part count = +17us (VGPR/occupancy cost > gain)
// => uniform-random 128B-line gather at ~2.9TB/s effective = fabric/L2-miss
// request-rate floor; ~250MB of unmergeable line requests across 3 layers
// ~ 90us + ~45us CSR scatter-build + ~12us dense + gaps ~= 190us floor.
// r7: big reg tiles crater occupancy. r9: LDS gemv is LDS-pipe-bound.
// MFMA layouts (guide m89/m97). cidx u16 (N_NODES=50000<65536).
// NOTE: no hipMemsetAsync — rocclr fillBuffer took 45.9us for 195KB in-graph.
// ---------------------------------------------------------------------------

#define DF 64
#define TB 256
#define NPART 8

typedef __attribute__((ext_vector_type(8))) short bf16x8;
typedef __attribute__((ext_vector_type(4))) float f32x4;

__device__ __forceinline__ unsigned short f2bf(float f) {
    union { float f; unsigned u; } c; c.f = f;
    unsigned u = c.u;
    return (unsigned short)((u + 0x7fffu + ((u >> 16) & 1u)) >> 16);   // RNE
}
__device__ __forceinline__ float bf2f(unsigned short h) {
    union { unsigned u; float f; } c; c.u = ((unsigned)h) << 16;
    return c.f;
}
__device__ __forceinline__ void acc_bf16x8(uint4 v, float* a) {
    a[0] += bf2f((unsigned short)(v.x & 0xffffu));
    a[1] += bf2f((unsigned short)(v.x >> 16));
    a[2] += bf2f((unsigned short)(v.y & 0xffffu));
    a[3] += bf2f((unsigned short)(v.y >> 16));
    a[4] += bf2f((unsigned short)(v.z & 0xffffu));
    a[5] += bf2f((unsigned short)(v.z >> 16));
    a[6] += bf2f((unsigned short)(v.w & 0xffffu));
    a[7] += bf2f((unsigned short)(v.w >> 16));
}
__device__ __forceinline__ void acc_bf16x4(uint2 v, float* a) {
    a[0] += bf2f((unsigned short)(v.x & 0xffffu));
    a[1] += bf2f((unsigned short)(v.x >> 16));
    a[2] += bf2f((unsigned short)(v.y & 0xffffu));
    a[3] += bf2f((unsigned short)(v.y >> 16));
}

__global__ void zero_int_kernel(int* __restrict__ p, int n) {
    int i = blockIdx.x * blockDim.x + threadIdx.x;
    if (i < n) p[i] = 0;
}

__global__ void count_deg_part_kernel(const int* __restrict__ dst, int* __restrict__ deg,
                                      int e, int psize) {
    const int p   = blockIdx.x & (NPART - 1);
    const int sl  = blockIdx.x / NPART;
    const int nsl = gridDim.x / NPART;
    const int lo = p * psize, hi = lo + psize;
    for (int i = sl * TB + threadIdx.x; i < e; i += nsl * TB) {
        int d = dst[i];
        if (d >= lo && d < hi) atomicAdd(&deg[d], 1);
    }
}

// per-block exclusive scan of deg -> ex (partial), block totals -> bsum; also dinv
__global__ void scan_block_kernel(const int* __restrict__ deg, int* __restrict__ ex,
                                  int* __restrict__ bsum, float* __restrict__ dinv, int n) {
    __shared__ int s[TB];
    const int t = threadIdx.x;
    const int i = blockIdx.x * TB + t;
    int v = (i < n) ? deg[i] : 0;
    if (i < n) dinv[i] = rsqrtf((float)(v + 1));   // +1 self-loop
    s[t] = v; __syncthreads();
#pragma unroll
    for (int o = 1; o < TB; o <<= 1) {
        int u = (t >= o) ? s[t - o] : 0;
        __syncthreads();
        s[t] += u;
        __syncthreads();
    }
    if (i < n) ex[i] = s[t] - v;
    if (t == TB - 1) bsum[blockIdx.x] = s[TB - 1];
}

// each block redundantly scans bsum (nb <= 256) in LDS, then offsets its slice
__global__ void add_offsets_kernel(int* __restrict__ ex, const int* __restrict__ bsum,
                                   int* __restrict__ cursor, int n, int nb) {
    __shared__ int s[TB];
    const int t = threadIdx.x;
    int v = (t < nb) ? bsum[t] : 0;
    s[t] = v; __syncthreads();
#pragma unroll
    for (int o = 1; o < TB; o <<= 1) {
        int u = (t >= o) ? s[t - o] : 0;
        __syncthreads();
        s[t] += u;
        __syncthreads();
    }
    const int boff = (blockIdx.x > 0) ? s[blockIdx.x - 1] : 0;
    const int i = blockIdx.x * TB + t;
    if (i < n) {
        int r = ex[i] + boff;
        ex[i] = r;
        cursor[i] = r;
    }
}

__global__ void fill_csr_part_kernel(const int* __restrict__ src, const int* __restrict__ dst,
                                     int* __restrict__ cursor,
                                     unsigned short* __restrict__ cidx, int e, int psize) {
    const int p   = blockIdx.x & (NPART - 1);
    const int sl  = blockIdx.x / NPART;
    const int nsl = gridDim.x / NPART;
    const int lo = p * psize, hi = lo + psize;
    for (int i = sl * TB + threadIdx.x; i < e; i += nsl * TB) {
        int d = dst[i];
        if (d >= lo && d < hi) {
            int pos = atomicAdd(&cursor[d], 1);
            cidx[pos] = (unsigned short)src[i];
        }
    }
}

// G[M x 64](bf16) = (X[M x 64] @ W1[64 x 64]) * dinv[row], via MFMA. Layer 1.
__global__ __launch_bounds__(256) void gemm_mfma_kernel(
        const float* __restrict__ X, const float* __restrict__ W,
        const float* __restrict__ dinv, unsigned short* __restrict__ G, int M) {
    const int lane = threadIdx.x & 63;
    const int wid  = threadIdx.x >> 6;         // 0..3
    const int t    = blockIdx.x * 4 + wid;     // row-tile index
    const int nt   = (M + 15) >> 4;
    if (t >= nt) return;
    const int n = lane & 15;
    const int g = lane >> 4;

    bf16x8 bf[4][2];
#pragma unroll
    for (int ct = 0; ct < 4; ++ct) {
        const int c = ct * 16 + n;
#pragma unroll
        for (int ks = 0; ks < 2; ++ks)
#pragma unroll
            for (int j = 0; j < 8; ++j)
                bf[ct][ks][j] = (short)f2bf(W[(ks * 32 + g * 8 + j) * 64 + c]);
    }

    const int row_a = t * 16 + n;
    const int ra = (row_a < M) ? row_a : (M - 1);
    bf16x8 af[2];
#pragma unroll
    for (int ks = 0; ks < 2; ++ks) {
        float4 p0 = *(const float4*)(X + (size_t)ra * 64 + ks * 32 + g * 8);
        float4 p1 = *(const float4*)(X + (size_t)ra * 64 + ks * 32 + g * 8 + 4);
        af[ks][0] = (short)f2bf(p0.x); af[ks][1] = (short)f2bf(p0.y);
        af[ks][2] = (short)f2bf(p0.z); af[ks][3] = (short)f2bf(p0.w);
        af[ks][4] = (short)f2bf(p1.x); af[ks][5] = (short)f2bf(p1.y);
        af[ks][6] = (short)f2bf(p1.z); af[ks][7] = (short)f2bf(p1.w);
    }

    const int rbase = t * 16 + g * 4;
    float di[4];
#pragma unroll
    for (int r = 0; r < 4; ++r) {
        int rr = rbase + r;
        di[r] = dinv[(rr < M) ? rr : (M - 1)];
    }

#pragma unroll
    for (int ct = 0; ct < 4; ++ct) {
        f32x4 acc = {0.f, 0.f, 0.f, 0.f};
        acc = __builtin_amdgcn_mfma_f32_16x16x32_bf16(af[0], bf[ct][0], acc, 0, 0, 0);
        acc = __builtin_amdgcn_mfma_f32_16x16x32_bf16(af[1], bf[ct][1], acc, 0, 0, 0);
        const int col = ct * 16 + n;
#pragma unroll
        for (int r = 0; r < 4; ++r) {
            const int row = rbase + r;
            if (row < M)
                G[(size_t)row * 64 + col] = f2bf(acc[r] * di[r]);
        }
    }
}

// Fused: aggregate 16 nodes (2 per wave, 8 waves, chains interleaved) +
// next-layer MFMA GEMM.
template <int NCO>
__global__ __launch_bounds__(512) void aggmm_kernel(
        const unsigned short* __restrict__ G,
        const int* __restrict__ rowptr, const int* __restrict__ deg,
        const unsigned short* __restrict__ cidx,
        const float* __restrict__ dinv, const float* __restrict__ b,
        const float* __restrict__ Wn,
        unsigned short* __restrict__ Gout, int M) {
    __shared__ unsigned short Ys[16][72];      // +8 pad: stride 144B
    __shared__ float ds[16];
    const int tid  = threadIdx.x;
    const int lane = tid & 63;
    const int wid  = tid >> 6;                 // 0..7
    const int base = blockIdx.x * 16;
    const int grp = lane >> 3;                 // 0..7 edge slot
    const int sub = lane & 7;                  // 0..7 col octet
    const int n16 = lane & 15;
    const int g16 = lane >> 4;

    // B fragments for MFMA waves (col tile = wid), loaded before agg
    const bool wactive = (wid * 16 < NCO);     // wid<4 (64) or wid<3 (40)
    bf16x8 bf[2];
    if (wactive) {
        const int c = wid * 16 + n16;
#pragma unroll
        for (int ks = 0; ks < 2; ++ks)
#pragma unroll
            for (int j = 0; j < 8; ++j) {
                const int k = ks * 32 + g16 * 8 + j;
                float w = (c < NCO) ? Wn[k * NCO + c] : 0.f;
                bf[ks][j] = (short)f2bf(w);
            }
    }

    // agg phase: wave wid owns rows wid*2, wid*2+1; chains interleaved
    const int nrow0 = wid * 2;
    const int node0 = min(base + nrow0, M - 1);        // clamped: garbage ok
    const int node1 = min(base + nrow0 + 1, M - 1);
    const int start0 = rowptr[node0], cnt0 = deg[node0];
    const int start1 = rowptr[node1], cnt1 = deg[node1];

    float a0[8] = {0.f, 0.f, 0.f, 0.f, 0.f, 0.f, 0.f, 0.f};
    float a1[8] = {0.f, 0.f, 0.f, 0.f, 0.f, 0.f, 0.f, 0.f};

    if (cnt0 <= 64 && cnt1 <= 64) {
        // fast path: both cidx chunks up front, rounds issue both gathers
        int idx0 = (lane < cnt0) ? (int)cidx[start0 + lane] : 0;
        int idx1 = (lane < cnt1) ? (int)cidx[start1 + lane] : 0;
        const int cmax = max(cnt0, cnt1);
        for (int e = grp; ; e += 8) {
            const bool p0 = e < cnt0, p1 = e < cnt1;
            if (e >= cmax) break;
            int s0 = __shfl(idx0, e, 64);
            int s1 = __shfl(idx1, e, 64);
            if (p0) {
                uint4 v = *(const uint4*)(G + (size_t)s0 * 64 + sub * 8);
                acc_bf16x8(v, a0);
            }
            if (p1) {
                uint4 v = *(const uint4*)(G + (size_t)s1 * 64 + sub * 8);
                acc_bf16x8(v, a1);
            }
        }
    } else {
        // slow path (deg>64, rare): sequential chunked per node
        for (int which = 0; which < 2; ++which) {
            float* a = which ? a1 : a0;
            const int start = which ? start1 : start0;
            const int cnt   = which ? cnt1 : cnt0;
            for (int bs = 0; bs < cnt; bs += 64) {
                const int nthis = min(64, cnt - bs);
                int myidx = (lane < nthis) ? (int)cidx[start + bs + lane] : 0;
                for (int j = grp; j < nthis; j += 8) {
                    int s = __shfl(myidx, j, 64);
                    uint4 v = *(const uint4*)(G + (size_t)s * 64 + sub * 8);
                    acc_bf16x8(v, a);
                }
            }
        }
    }
    // butterflies (both nodes interleaved for ILP)
#pragma unroll
    for (int k = 0; k < 8; ++k) {
        a0[k] += __shfl_xor(a0[k], 8, 64);
        a1[k] += __shfl_xor(a1[k], 8, 64);
        a0[k] += __shfl_xor(a0[k], 16, 64);
        a1[k] += __shfl_xor(a1[k], 16, 64);
        a0[k] += __shfl_xor(a0[k], 32, 64);
        a1[k] += __shfl_xor(a1[k], 32, 64);
    }
    if (grp == 0) {
#pragma unroll
        for (int i = 0; i < 2; ++i) {
            const float* a = i ? a1 : a0;
            const int node = i ? node1 : node0;
            uint4 sv = *(const uint4*)(G + (size_t)node * 64 + sub * 8);
            float4 b0 = *(const float4*)(b + sub * 8);
            float4 b1 = *(const float4*)(b + sub * 8 + 4);
            const float di = dinv[node];
            float v[8];
            v[0] = fmaxf((a[0] + bf2f((unsigned short)(sv.x & 0xffffu))) * di + b0.x, 0.f);
            v[1] = fmaxf((a[1] + bf2f((unsigned short)(sv.x >> 16)))     * di + b0.y, 0.f);
            v[2] = fmaxf((a[2] + bf2f((unsigned short)(sv.y & 0xffffu))) * di + b0.z, 0.f);
            v[3] = fmaxf((a[3] + bf2f((unsigned short)(sv.y >> 16)))     * di + b0.w, 0.f);
            v[4] = fmaxf((a[4] + bf2f((unsigned short)(sv.z & 0xffffu))) * di + b1.x, 0.f);
            v[5] = fmaxf((a[5] + bf2f((unsigned short)(sv.z >> 16)))     * di + b1.y, 0.f);
            v[6] = fmaxf((a[6] + bf2f((unsigned short)(sv.w & 0xffffu))) * di + b1.z, 0.f);
            v[7] = fmaxf((a[7] + bf2f((unsigned short)(sv.w >> 16)))     * di + b1.w, 0.f);
            uint4 o;
            o.x = (unsigned)f2bf(v[0]) | ((unsigned)f2bf(v[1]) << 16);
            o.y = (unsigned)f2bf(v[2]) | ((unsigned)f2bf(v[3]) << 16);
            o.z = (unsigned)f2bf(v[4]) | ((unsigned)f2bf(v[5]) << 16);
            o.w = (unsigned)f2bf(v[6]) | ((unsigned)f2bf(v[7]) << 16);
            *((uint4*)&Ys[nrow0 + i][sub * 8]) = o;
            if (sub == 0) ds[nrow0 + i] = di;
        }
    }
    __syncthreads();

    // MFMA phase: wave wid (<NCO/16) -> col tile [wid*16, wid*16+16)
    if (!wactive) return;
    bf16x8 af[2];
#pragma unroll
    for (int ks = 0; ks < 2; ++ks)
        af[ks] = *(const bf16x8*)&Ys[n16][ks * 32 + g16 * 8];
    f32x4 acc = {0.f, 0.f, 0.f, 0.f};
    acc = __builtin_amdgcn_mfma_f32_16x16x32_bf16(af[0], bf[0], acc, 0, 0, 0);
    acc = __builtin_amdgcn_mfma_f32_16x16x32_bf16(af[1], bf[1], acc, 0, 0, 0);
    const int col = wid * 16 + n16;
#pragma unroll
    for (int r = 0; r < 4; ++r) {
        const int row = base + g16 * 4 + r;
        if (row < M && col < NCO)
            Gout[(size_t)row * NCO + col] = f2bf(acc[r] * ds[g16 * 4 + r]);
    }
}

// NC=40 aggregation + fused log_softmax. lane = grp(2b)*16 + sub(4b);
// lane owns cols [sub*4, sub*4+4); 4 edge rows per instruction.
__global__ void agg40_lsm_kernel(const unsigned short* __restrict__ G,
                                 const int* __restrict__ rowptr, const int* __restrict__ deg,
                                 const unsigned short* __restrict__ cidx,
                                 const float* __restrict__ dinv, const float* __restrict__ b,
                                 float* __restrict__ Y, int M) {
    constexpr int NC = 40;
    constexpr int NQ = 10;
    const int lane = threadIdx.x & 63;
    const int node = blockIdx.x * 4 + (threadIdx.x >> 6);
    if (node >= M) return;
    const int grp = lane >> 4;                 // 0..3
    const int sub = lane & 15;                 // 0..15
    const bool act = (sub < NQ);
    const int start = rowptr[node];
    const int cnt = deg[node];

    float a[4] = {0.f, 0.f, 0.f, 0.f};
    float c[4] = {0.f, 0.f, 0.f, 0.f};

    for (int base = 0; base < cnt; base += 64) {
        const int nthis = min(64, cnt - base);
        int myidx = (lane < nthis) ? (int)cidx[start + base + lane] : 0;
        int j = 0;
        for (; j + 8 <= nthis; j += 8) {
            int s0 = __shfl(myidx, j + grp, 64);
            int s1 = __shfl(myidx, j + 4 + grp, 64);
            if (act) {
                uint2 v0 = *(const uint2*)(G + (size_t)s0 * NC + sub * 4);
                uint2 v1 = *(const uint2*)(G + (size_t)s1 * NC + sub * 4);
                acc_bf16x4(v0, a);
                acc_bf16x4(v1, c);
            }
        }
        if (j + 4 <= nthis) {
            int s0 = __shfl(myidx, j + grp, 64);
            if (act) {
                uint2 v0 = *(const uint2*)(G + (size_t)s0 * NC + sub * 4);
                acc_bf16x4(v0, a);
            }
            j += 4;
        }
        const int rem = nthis - j;             // 0..3
        if (grp < rem) {
            int s0 = __shfl(myidx, j + grp, 64);
            if (act) {
                uint2 v0 = *(const uint2*)(G + (size_t)s0 * NC + sub * 4);
                acc_bf16x4(v0, c);
            }
        }
    }
#pragma unroll
    for (int k = 0; k < 4; ++k) a[k] += c[k];
#pragma unroll
    for (int k = 0; k < 4; ++k) {
        a[k] += __shfl_xor(a[k], 16, 64);
        a[k] += __shfl_xor(a[k], 32, 64);
    }
    float v[4];
    {
        float self[4] = {0.f, 0.f, 0.f, 0.f};
        float4 bb = make_float4(0.f, 0.f, 0.f, 0.f);
        if (act) {
            uint2 sv = *(const uint2*)(G + (size_t)node * NC + sub * 4);
            self[0] = bf2f((unsigned short)(sv.x & 0xffffu));
            self[1] = bf2f((unsigned short)(sv.x >> 16));
            self[2] = bf2f((unsigned short)(sv.y & 0xffffu));
            self[3] = bf2f((unsigned short)(sv.y >> 16));
            bb = *(const float4*)(b + sub * 4);
        }
        const float di = dinv[node];
        v[0] = fmaxf((a[0] + self[0]) * di + bb.x, 0.f);
        v[1] = fmaxf((a[1] + self[1]) * di + bb.y, 0.f);
        v[2] = fmaxf((a[2] + self[2]) * di + bb.z, 0.f);
        v[3] = fmaxf((a[3] + self[3]) * di + bb.w, 0.f);
    }
    float m = act ? fmaxf(fmaxf(v[0], v[1]), fmaxf(v[2], v[3])) : -INFINITY;
#pragma unroll
    for (int o = 1; o < 16; o <<= 1) m = fmaxf(m, __shfl_xor(m, o, 64));
    float es = act ? (expf(v[0] - m) + expf(v[1] - m) + expf(v[2] - m) + expf(v[3] - m)) : 0.f;
#pragma unroll
    for (int o = 1; o < 16; o <<= 1) es += __shfl_xor(es, o, 64);
    const float ls = logf(es);
    if (act && grp == 0) {
        *((float4*)(Y + (size_t)node * NC + sub * 4)) =
            make_float4(v[0] - m - ls, v[1] - m - ls, v[2] - m - ls, v[3] - m - ls);
    }
}

extern "C" void kernel_launch(void* const* d_in, const int* in_sizes, int n_in,
                              void* d_out, int out_size, void* d_ws, size_t ws_size,
                              hipStream_t stream) {
    const float* x  = (const float*)d_in[0];
    const int*   ei = (const int*)d_in[1];        // [2, E] int32
    const float* W1 = (const float*)d_in[2];
    const float* b1 = (const float*)d_in[3];
    const float* W2 = (const float*)d_in[4];
    const float* b2 = (const float*)d_in[5];
    const float* W3 = (const float*)d_in[6];
    const float* b3 = (const float*)d_in[7];
    float* out = (float*)d_out;

    const int M  = in_sizes[0] / DF;              // 50000
    const int E  = in_sizes[1] / 2;               // 800000
    (void)ws_size; (void)n_in; (void)out_size;

    const int* src = ei;
    const int* dst = ei + E;

    const size_t Ma = ((size_t)M + 63) & ~63ull;
    const size_t Ea = ((size_t)E + 63) & ~63ull;

    // workspace layout
    int* deg    = (int*)d_ws;                            // Ma
    int* rowptr = deg + Ma;                              // Ma
    int* cursor = rowptr + Ma;                           // Ma
    int* bsum   = cursor + Ma;                           // 256
    unsigned short* cidx = (unsigned short*)(bsum + 256);        // Ea (u16)
    float* dinv = (float*)(cidx + Ea);                   // Ma
    unsigned short* G0 = (unsigned short*)(dinv + Ma);           // Ma*64 (bf16)
    unsigned short* G1 = G0 + Ma * DF;                   // Ma*64 (bf16)

    const int gN = (M + TB - 1) / TB;
    const int nb = gN;                   // scan blocks (196 <= 256)
    const int psize = (M + NPART - 1) / NPART;
    const int partGrd = NPART * 96;      // 8 partitions x 96 slices

    // --- CSR build + dinv (once, reused by all 3 layers) ---
    zero_int_kernel<<<gN, TB, 0, stream>>>(deg, M);
    count_deg_part_kernel<<<partGrd, TB, 0, stream>>>(dst, deg, E, psize);
    scan_block_kernel<<<nb, TB, 0, stream>>>(deg, rowptr, bsum, dinv, M);
    add_offsets_kernel<<<nb, TB, 0, stream>>>(rowptr, bsum, cursor, M, nb);
    fill_csr_part_kernel<<<partGrd, TB, 0, stream>>>(src, dst, cursor, cidx, E, psize);

    const int nt      = (M + 15) / 16;            // 16-row tiles
    const int gemmGrd = (nt + 3) / 4;             // 4 waves/block (layer-1 gemm)
    const int fusGrd  = nt;                       // 16 nodes/block (fused)
    const int aggGrd  = (M + 3) / 4;

    // layer-1 dense transform
    gemm_mfma_kernel<<<gemmGrd, TB, 0, stream>>>(x, W1, dinv, G0, M);
    // layer-1 aggregate + layer-2 GEMM (fused; interleaved 2-node chains)
    aggmm_kernel<64><<<fusGrd, 512, 0, stream>>>(G0, rowptr, deg, cidx, dinv, b1, W2, G1, M);
    // layer-2 aggregate + layer-3 GEMM (fused)
    aggmm_kernel<40><<<fusGrd, 512, 0, stream>>>(G1, rowptr, deg, cidx, dinv, b2, W3, G0, M);
    // layer-3 aggregate + log_softmax
    agg40_lsm_kernel<<<aggGrd, TB, 0, stream>>>(G0, rowptr, deg, cidx, dinv, b3, out, M);
}